// Round 1
// baseline (672.881 us; speedup 1.0000x reference)
//
#include <hip/hip_runtime.h>
#include <math.h>

#define NT 128
#define NB 16
#define TT 8
#define C 512
#define RR 64
#define HW 784
#define HH 28
#define WW 28
#define PP 3
#define NN 24
#define EPS 1e-5f

// ---------------- Kernel A: conv1 (1x1x1, C->64) + BN + LReLU ----------------
// GEMM per nt: M=784(hw) x N=64(r) x K=512(c). 64-hw tile per block.
__global__ __launch_bounds__(256) void convA(const float* __restrict__ X,
        const float* __restrict__ W1, const float* __restrict__ cb,
        const float* __restrict__ g, const float* __restrict__ bb,
        const float* __restrict__ m, const float* __restrict__ v,
        float* __restrict__ s1)
{
    __shared__ float Xs[32][64];   // k-major x hw
    __shared__ float Ws[32][68];   // k-major x r (pad 68 to break store conflicts, keep 16B align)
    const int nt  = blockIdx.y;
    const int hw0 = blockIdx.x * 64;
    const int tid = threadIdx.x;
    const int tr = tid & 15;   // hw group
    const int tc = tid >> 4;   // r group
    float acc[4][4] = {};
    const float* Xnt = X + (size_t)nt * C * HW;

    for (int k0 = 0; k0 < C; k0 += 32) {
        #pragma unroll
        for (int i = 0; i < 8; ++i) {
            int idx = tid + i * 256;          // 0..2047
            int kl = idx >> 6, hwl = idx & 63;
            int hw = hw0 + hwl;
            Xs[kl][hwl] = (hw < HW) ? Xnt[(k0 + kl) * HW + hw] : 0.f;
        }
        #pragma unroll
        for (int i = 0; i < 8; ++i) {
            int idx = tid + i * 256;
            int kl = idx & 31, r = idx >> 5;  // r 0..63
            Ws[kl][r] = W1[r * C + k0 + kl];
        }
        __syncthreads();
        #pragma unroll
        for (int k = 0; k < 32; ++k) {
            float4 xv = *(const float4*)&Xs[k][tr * 4];
            float4 wv = *(const float4*)&Ws[k][tc * 4];
            acc[0][0] += xv.x * wv.x; acc[0][1] += xv.x * wv.y;
            acc[0][2] += xv.x * wv.z; acc[0][3] += xv.x * wv.w;
            acc[1][0] += xv.y * wv.x; acc[1][1] += xv.y * wv.y;
            acc[1][2] += xv.y * wv.z; acc[1][3] += xv.y * wv.w;
            acc[2][0] += xv.z * wv.x; acc[2][1] += xv.z * wv.y;
            acc[2][2] += xv.z * wv.z; acc[2][3] += xv.z * wv.w;
            acc[3][0] += xv.w * wv.x; acc[3][1] += xv.w * wv.y;
            acc[3][2] += xv.w * wv.z; acc[3][3] += xv.w * wv.w;
        }
        __syncthreads();
    }
    #pragma unroll
    for (int j = 0; j < 4; ++j) {
        int r = tc * 4 + j;
        float inv = g[r] / sqrtf(v[r] + EPS);
        float add = bb[r] - m[r] * inv;
        float cbr = cb[r];
        #pragma unroll
        for (int i = 0; i < 4; ++i) {
            int hw = hw0 + tr * 4 + i;
            if (hw < HW) {
                float y = (acc[i][j] + cbr) * inv + add;
                s1[((size_t)nt * RR + r) * HW + hw] = (y >= 0.f) ? y : 0.05f * y;
            }
        }
    }
}

// ---------------- Kernel B: conv2 (3x1x1 over t, 64->64) + bias ----------------
__global__ __launch_bounds__(256) void convB(const float* __restrict__ s1,
        const float* __restrict__ W2, const float* __restrict__ cb,
        float* __restrict__ s2)
{
    __shared__ float Xs[32][64];
    __shared__ float Ws[32][68];
    const int nt = blockIdx.y;
    const int n = nt >> 3, t = nt & 7;
    const int hw0 = blockIdx.x * 64;
    const int tid = threadIdx.x;
    const int tr = tid & 15, tc = tid >> 4;
    float acc[4][4] = {};

    for (int dt = 0; dt < 3; ++dt) {
        int tp = t + dt - 1;
        if (tp < 0 || tp >= TT) continue;   // uniform per block
        const float* Sp = s1 + (size_t)(n * TT + tp) * RR * HW;
        for (int k0 = 0; k0 < RR; k0 += 32) {
            #pragma unroll
            for (int i = 0; i < 8; ++i) {
                int idx = tid + i * 256;
                int kl = idx >> 6, hwl = idx & 63;
                int hw = hw0 + hwl;
                Xs[kl][hwl] = (hw < HW) ? Sp[(k0 + kl) * HW + hw] : 0.f;
            }
            #pragma unroll
            for (int i = 0; i < 8; ++i) {
                int idx = tid + i * 256;
                int kl = idx & 31, r = idx >> 5;
                Ws[kl][r] = W2[r * 192 + (k0 + kl) * 3 + dt];
            }
            __syncthreads();
            #pragma unroll
            for (int k = 0; k < 32; ++k) {
                float4 xv = *(const float4*)&Xs[k][tr * 4];
                float4 wv = *(const float4*)&Ws[k][tc * 4];
                acc[0][0] += xv.x * wv.x; acc[0][1] += xv.x * wv.y;
                acc[0][2] += xv.x * wv.z; acc[0][3] += xv.x * wv.w;
                acc[1][0] += xv.y * wv.x; acc[1][1] += xv.y * wv.y;
                acc[1][2] += xv.y * wv.z; acc[1][3] += xv.y * wv.w;
                acc[2][0] += xv.z * wv.x; acc[2][1] += xv.z * wv.y;
                acc[2][2] += xv.z * wv.z; acc[2][3] += xv.z * wv.w;
                acc[3][0] += xv.w * wv.x; acc[3][1] += xv.w * wv.y;
                acc[3][2] += xv.w * wv.z; acc[3][3] += xv.w * wv.w;
            }
            __syncthreads();
        }
    }
    #pragma unroll
    for (int j = 0; j < 4; ++j) {
        int r = tc * 4 + j;
        float cbr = cb[r];
        #pragma unroll
        for (int i = 0; i < 4; ++i) {
            int hw = hw0 + tr * 4 + i;
            if (hw < HW)
                s2[((size_t)nt * RR + r) * HW + hw] = acc[i][j] + cbr;
        }
    }
}

// ---------------- Kernel C: conv3 (1x5x5, 64->3, pad 2) + BN + sigmoid ----------------
// One block per (nt, row-half). Thread = 1 row x 2 cols strip, 3 p-channels.
__global__ __launch_bounds__(256) void convC(const float* __restrict__ s2,
        const float* __restrict__ W3, const float* __restrict__ cb,
        const float* __restrict__ g, const float* __restrict__ bb,
        const float* __restrict__ m, const float* __restrict__ v,
        float* __restrict__ smap)
{
    __shared__ float tile[8][18][36];  // 8 r' x 18 rows x (28 cols + halo/pad), col c at slot c+2
    const int nt = blockIdx.y;
    const int half = blockIdx.x;
    const int tid = threadIdx.x;
    const int row0 = half * 14 - 2;    // input row stored at slot 0
    const int orl = tid / 14;          // 0..13 when tid<196
    const int wsi = tid % 14;
    const int orow = half * 14 + orl;
    const int w0 = wsi * 2;
    float acc[3][2] = {};
    const float* S = s2 + (size_t)nt * RR * HW;

    for (int rc0 = 0; rc0 < RR; rc0 += 8) {
        for (int i = 0; i < 21; ++i) {
            int idx = tid + i * 256;
            if (idx < 5184) {
                int rl = idx / 648;
                int rem = idx - rl * 648;
                int rr = rem / 36;
                int cs = rem - rr * 36;
                int grow = row0 + rr;
                int c = cs - 2;
                float val = 0.f;
                if (grow >= 0 && grow < HH && c >= 0 && c < WW)
                    val = S[(rc0 + rl) * HW + grow * WW + c];
                tile[rl][rr][cs] = val;
            }
        }
        __syncthreads();
        if (tid < 196) {
            #pragma unroll
            for (int rl = 0; rl < 8; ++rl) {
                const float* wr = W3 + (rc0 + rl) * 25;
                #pragma unroll
                for (int dh = 0; dh < 5; ++dh) {
                    const float* trow = &tile[rl][orl + dh][w0];
                    float inb[6];
                    #pragma unroll
                    for (int q = 0; q < 6; ++q) inb[q] = trow[q];
                    #pragma unroll
                    for (int dw = 0; dw < 5; ++dw) {
                        float v0 = inb[dw], v1 = inb[dw + 1];
                        #pragma unroll
                        for (int p = 0; p < 3; ++p) {
                            float wv = wr[p * 1600 + dh * 5 + dw];  // wave-uniform -> scalar load
                            acc[p][0] += v0 * wv;
                            acc[p][1] += v1 * wv;
                        }
                    }
                }
            }
        }
        __syncthreads();
    }
    if (tid < 196) {
        #pragma unroll
        for (int p = 0; p < 3; ++p) {
            float inv = g[p] / sqrtf(v[p] + EPS);
            float add = bb[p] - m[p] * inv;
            #pragma unroll
            for (int j = 0; j < 2; ++j) {
                float z = (acc[p][j] + cb[p]) * inv + add;
                float sg = 1.f / (1.f + expf(-z));
                smap[((size_t)nt * PP + p) * HW + orow * WW + w0 + j] = sg;
            }
        }
    }
}

// ---------------- Kernel D: weighted node pooling + residual mean ----------------
// One wave per (nt, c): nodes[n,t,p,c] and residual -> out rows 1..8
__global__ __launch_bounds__(256) void poolD(const float* __restrict__ X,
        const float* __restrict__ smap, float* __restrict__ nodes,
        float* __restrict__ out)
{
    const int tid = threadIdx.x;
    const int lane = tid & 63;
    const int gw = blockIdx.x * 4 + (tid >> 6);
    const int c = gw & 511;
    const int nt = gw >> 9;
    const float4* X4 = (const float4*)(X + ((size_t)nt * C + c) * HW);
    const float4* S0 = (const float4*)(smap + (size_t)nt * PP * HW);
    const float4* S1 = S0 + 196;
    const float4* S2 = S1 + 196;
    float sx = 0.f, a0 = 0.f, a1 = 0.f, a2 = 0.f;
    #pragma unroll
    for (int i = 0; i < 4; ++i) {
        int fi = i * 64 + lane;
        if (fi < 196) {
            float4 x = X4[fi];
            float4 p0 = S0[fi], p1 = S1[fi], p2 = S2[fi];
            sx += x.x + x.y + x.z + x.w;
            a0 += x.x * p0.x + x.y * p0.y + x.z * p0.z + x.w * p0.w;
            a1 += x.x * p1.x + x.y * p1.y + x.z * p1.z + x.w * p1.w;
            a2 += x.x * p2.x + x.y * p2.y + x.z * p2.z + x.w * p2.w;
        }
    }
    #pragma unroll
    for (int off = 32; off >= 1; off >>= 1) {
        sx += __shfl_xor(sx, off);
        a0 += __shfl_xor(a0, off);
        a1 += __shfl_xor(a1, off);
        a2 += __shfl_xor(a2, off);
    }
    if (lane == 0) {
        int n = nt >> 3, t = nt & 7;
        const float s = 1.f / 784.f;
        out[((size_t)n * 9 + 1 + t) * C + c] = sx * s;
        float* nd = nodes + ((size_t)n * NN + t * PP) * C + c;
        nd[0]     = a0 * s;
        nd[C]     = a1 * s;
        nd[2 * C] = a2 * s;
    }
}

// ---------------- Kernel E1: A = nodes nodes^T / C, normalized Laplacian L ----------------
__global__ __launch_bounds__(256) void graphL(const float* __restrict__ nodes,
        float* __restrict__ Lg)
{
    __shared__ float4 nds[24][129];   // 24 x 512 floats, padded pitch
    __shared__ float Amat[24][24];
    __shared__ float dinv[24];
    const int n = blockIdx.x;
    const int tid = threadIdx.x;
    const float4* src = (const float4*)(nodes + (size_t)n * NN * C);
    #pragma unroll
    for (int i = 0; i < 12; ++i) {
        int fi = tid + i * 256;       // 0..3071
        int row = fi >> 7, k4 = fi & 127;
        nds[row][k4] = src[row * 128 + k4];
    }
    __syncthreads();
    for (int pair = tid; pair < 576; pair += 256) {
        int i = pair / 24, j = pair - (pair / 24) * 24;
        const float4* ri = &nds[i][0];
        const float4* rj = &nds[j][0];
        float s = 0.f;
        for (int k = 0; k < 128; ++k) {
            float4 a = ri[k], b = rj[k];
            s += a.x * b.x + a.y * b.y + a.z * b.z + a.w * b.w;
        }
        Amat[i][j] = s * (1.f / 512.f);
    }
    __syncthreads();
    if (tid < 24) {
        float d = 0.f;
        for (int j = 0; j < 24; ++j) d += Amat[tid][j];
        d = fmaxf(d, 1e-8f);
        dinv[tid] = 1.f / sqrtf(d);
    }
    __syncthreads();
    for (int pair = tid; pair < 576; pair += 256) {
        int i = pair / 24, j = pair - (pair / 24) * 24;
        Lg[(size_t)n * 576 + pair] = dinv[i] * Amat[i][j] * dinv[j];
    }
}

// ---------------- Kernel G: Y[384,512] = Xin[384,512] @ W^T (W [512,512] row-major o,k) ----
__global__ __launch_bounds__(256) void gemmG(const float* __restrict__ Xin,
        const float* __restrict__ Wm, float* __restrict__ Y)
{
    __shared__ float Xs[32][36];  // k-major x m
    __shared__ float Ws[32][66];  // k-major x o
    const int o0 = blockIdx.x * 64;
    const int m0 = blockIdx.y * 32;
    const int tid = threadIdx.x;
    const int tr = tid >> 5;   // 0..7  (m groups of 4)
    const int tc = tid & 31;   // 0..31 (o groups of 2)
    float acc[4][2] = {};

    for (int k0 = 0; k0 < 512; k0 += 32) {
        {
            int ml = tid >> 3, k4 = tid & 7;
            float4 xv = *(const float4*)&Xin[(size_t)(m0 + ml) * 512 + k0 + k4 * 4];
            Xs[k4 * 4 + 0][ml] = xv.x; Xs[k4 * 4 + 1][ml] = xv.y;
            Xs[k4 * 4 + 2][ml] = xv.z; Xs[k4 * 4 + 3][ml] = xv.w;
        }
        #pragma unroll
        for (int i = 0; i < 2; ++i) {
            int idx = tid + i * 256;
            int ol = idx >> 3, k4 = idx & 7;
            float4 wv = *(const float4*)&Wm[(size_t)(o0 + ol) * 512 + k0 + k4 * 4];
            Ws[k4 * 4 + 0][ol] = wv.x; Ws[k4 * 4 + 1][ol] = wv.y;
            Ws[k4 * 4 + 2][ol] = wv.z; Ws[k4 * 4 + 3][ol] = wv.w;
        }
        __syncthreads();
        #pragma unroll
        for (int k = 0; k < 32; ++k) {
            float4 xv = *(const float4*)&Xs[k][tr * 4];
            float2 wv = *(const float2*)&Ws[k][tc * 2];
            acc[0][0] += xv.x * wv.x; acc[0][1] += xv.x * wv.y;
            acc[1][0] += xv.y * wv.x; acc[1][1] += xv.y * wv.y;
            acc[2][0] += xv.z * wv.x; acc[2][1] += xv.z * wv.y;
            acc[3][0] += xv.w * wv.x; acc[3][1] += xv.w * wv.y;
        }
        __syncthreads();
    }
    #pragma unroll
    for (int i2 = 0; i2 < 4; ++i2)
        #pragma unroll
        for (int j = 0; j < 2; ++j)
            Y[(size_t)(m0 + tr * 4 + i2) * 512 + o0 + tc * 2 + j] = acc[i2][j];
}

// ---------------- Kernel LX: Xg = lrelu(L @ G) per n ----------------
__global__ __launch_bounds__(256) void applyL(const float* __restrict__ G,
        const float* __restrict__ Lg, float* __restrict__ Xg)
{
    __shared__ float Ls[576];
    const int n = blockIdx.y;
    const int tid = threadIdx.x;
    for (int i = tid; i < 576; i += 256) Ls[i] = Lg[(size_t)n * 576 + i];
    __syncthreads();
    const int o = blockIdx.x * 128 + (tid & 127);
    const int ig = (tid >> 7) * 12;   // 0 or 12
    float acc[12] = {};
    const float* Gn = G + (size_t)n * NN * 512;
    for (int j = 0; j < 24; ++j) {
        float gv = Gn[j * 512 + o];
        #pragma unroll
        for (int i = 0; i < 12; ++i)
            acc[i] += Ls[(ig + i) * 24 + j] * gv;
    }
    float* Xn = Xg + (size_t)n * NN * 512;
    #pragma unroll
    for (int i = 0; i < 12; ++i) {
        float y = acc[i];
        Xn[(ig + i) * 512 + o] = (y >= 0.f) ? y : 0.05f * y;
    }
}

// ---------------- Kernel E4: attention readout -> out row 0 ----------------
__global__ __launch_bounds__(256) void attE(const float* __restrict__ Xg,
        const float* __restrict__ nodes, const float* __restrict__ Lg,
        const float* __restrict__ aw, const float* __restrict__ ab,
        float* __restrict__ out)
{
    __shared__ float zs[24], ys[24], att[24], Ls[576];
    const int n = blockIdx.x;
    const int tid = threadIdx.x;
    const int lane = tid & 63, wv = tid >> 6;
    for (int i = tid; i < 576; i += 256) Ls[i] = Lg[(size_t)n * 576 + i];
    const float* Xn = Xg + (size_t)n * NN * 512;
    const float* Nn = nodes + (size_t)n * NN * 512;
    for (int i = wv; i < 24; i += 4) {
        float s = 0.f;
        #pragma unroll
        for (int kk = 0; kk < 8; ++kk) {
            int k = kk * 64 + lane;
            s += (Xn[i * 512 + k] + Nn[i * 512 + k]) * aw[k];
        }
        #pragma unroll
        for (int off = 32; off >= 1; off >>= 1) s += __shfl_xor(s, off);
        if (lane == 0) zs[i] = s;
    }
    __syncthreads();
    if (tid < 24) {
        float y = ab[0];
        for (int j = 0; j < 24; ++j) y += Ls[tid * 24 + j] * zs[j];
        ys[tid] = y;
    }
    __syncthreads();
    if (tid < 64) {
        float vv = (tid < 24) ? ys[tid] : -3.4e38f;
        float mx = vv;
        #pragma unroll
        for (int off = 32; off >= 1; off >>= 1) mx = fmaxf(mx, __shfl_xor(mx, off));
        float e = (tid < 24) ? expf(vv - mx) : 0.f;
        float ssum = e;
        #pragma unroll
        for (int off = 32; off >= 1; off >>= 1) ssum += __shfl_xor(ssum, off);
        if (tid < 24) att[tid] = e / ssum;
    }
    __syncthreads();
    for (int c2 = tid; c2 < 512; c2 += 256) {
        float r = 0.f;
        #pragma unroll
        for (int i = 0; i < 24; ++i) r += Xn[i * 512 + c2] * att[i];
        out[(size_t)n * 9 * 512 + c2] = r;
    }
}

extern "C" void kernel_launch(void* const* d_in, const int* in_sizes, int n_in,
                              void* d_out, int out_size, void* d_ws, size_t ws_size,
                              hipStream_t stream)
{
    const float* X   = (const float*)d_in[0];
    const float* w1  = (const float*)d_in[1];
    const float* b1c = (const float*)d_in[2];
    const float* g1  = (const float*)d_in[3];
    const float* b1  = (const float*)d_in[4];
    const float* m1  = (const float*)d_in[5];
    const float* v1  = (const float*)d_in[6];
    const float* w2  = (const float*)d_in[7];
    const float* b2c = (const float*)d_in[8];
    const float* w3  = (const float*)d_in[9];
    const float* b3c = (const float*)d_in[10];
    const float* g2  = (const float*)d_in[11];
    const float* b2  = (const float*)d_in[12];
    const float* m2  = (const float*)d_in[13];
    const float* v2  = (const float*)d_in[14];
    const float* gw0 = (const float*)d_in[15];
    const float* gw1 = (const float*)d_in[16];
    const float* aw  = (const float*)d_in[17];
    const float* ab  = (const float*)d_in[18];
    float* out = (float*)d_out;

    float* ws    = (float*)d_ws;
    float* s1    = ws;
    float* s2    = s1 + (size_t)NT * RR * HW;
    float* smap  = s2 + (size_t)NT * RR * HW;
    float* nodes = smap + (size_t)NT * PP * HW;
    float* Lg    = nodes + (size_t)NB * NN * C;
    float* gt    = Lg + (size_t)NB * NN * NN;
    float* xa    = gt + (size_t)NB * NN * C;
    float* xb    = xa + (size_t)NB * NN * C;

    convA<<<dim3(13, NT), 256, 0, stream>>>(X, w1, b1c, g1, b1, m1, v1, s1);
    convB<<<dim3(13, NT), 256, 0, stream>>>(s1, w2, b2c, s2);
    convC<<<dim3(2, NT), 256, 0, stream>>>(s2, w3, b3c, g2, b2, m2, v2, smap);
    poolD<<<dim3(16384), 256, 0, stream>>>(X, smap, nodes, out);
    graphL<<<dim3(NB), 256, 0, stream>>>(nodes, Lg);
    gemmG<<<dim3(8, 12), 256, 0, stream>>>(nodes, gw0, gt);
    applyL<<<dim3(4, NB), 256, 0, stream>>>(gt, Lg, xa);
    gemmG<<<dim3(8, 12), 256, 0, stream>>>(xa, gw1, gt);
    applyL<<<dim3(4, NB), 256, 0, stream>>>(gt, Lg, xb);
    attE<<<dim3(NB), 256, 0, stream>>>(xb, nodes, Lg, aw, ab, out);
}

// Round 2
// 599.348 us; speedup vs baseline: 1.1227x; 1.1227x over previous
//
#include <hip/hip_runtime.h>
#include <hip/hip_bf16.h>
#include <math.h>

#define NT 128
#define NB 16
#define TT 8
#define C 512
#define RR 64
#define HW 784
#define HH 28
#define WW 28
#define PP 3
#define NN 24
#define EPS 1e-5f

typedef __attribute__((ext_vector_type(8))) short bh8;
typedef __attribute__((ext_vector_type(4))) float f32x4;

static __device__ inline unsigned short f2bf(float f) {
    __hip_bfloat16 h = __float2bfloat16(f);
    return *(unsigned short*)&h;
}
static __device__ inline float bf2f(unsigned short u) {
    __hip_bfloat16 h;
    *(unsigned short*)&h = u;
    return __bfloat162float(h);
}

// ---------------- Kernel A (MFMA): conv1 (1x1x1, C->64) + BN + LReLU ----------------
// Per block: nt, 64-wide hw tile. D[r][hw] = sum_c W[r][c] X[c][hw].
// A-operand = W (bf16 hi/lo, pre-packed fragments in LDS, ds_read_b128).
// B-operand = X (bf16 hi/lo in LDS [k][72], u16 gather per fragment).
// 3-term split: Wh*Xh + Wh*Xl + Wl*Xh  (error ~2^-17 rel, fp32-like).
__global__ __launch_bounds__(256) void convA_mfma(const float* __restrict__ X,
        const float* __restrict__ W1, const float* __restrict__ cb,
        const float* __restrict__ g, const float* __restrict__ bb,
        const float* __restrict__ m, const float* __restrict__ v,
        float* __restrict__ s1)
{
    __shared__ unsigned short Xh[32 * 72];
    __shared__ unsigned short Xl[32 * 72];
    __shared__ unsigned short Wh[4 * 64 * 8];   // [rt][lane][8k]
    __shared__ unsigned short Wl[4 * 64 * 8];
    __shared__ float sInv[64], sAdd[64], sCb[64];

    const int nt  = blockIdx.y;
    const int hw0 = blockIdx.x * 64;
    const int tid = threadIdx.x;

    if (tid < 64) {
        float inv = g[tid] * rsqrtf(v[tid] + EPS);
        sInv[tid] = inv;
        sAdd[tid] = bb[tid] - m[tid] * inv;
        sCb[tid]  = cb[tid];
    }

    // staging roles
    const int sk = tid >> 3;          // 0..31 (k row for X staging)
    const int ss = tid & 7;           // 0..7  (8-hw group)
    const int wr = tid >> 2;          // 0..63 (r for W staging)
    const int wj = tid & 3;           // 0..3  (k-octet)
    const bool full = (hw0 + 64 <= HW);

    // compute roles
    const int wv = tid >> 6;          // wave 0..3 -> hw 16-chunk
    const int l  = tid & 63;
    const int gq = l >> 4;            // lane group 0..3
    const int mm16 = l & 15;
    // X fragment element offsets: (8*gq + j)*72 + 16*wv + (mm16 ^ 8*(gq&1))
    const int xbase = (gq * 8) * 72 + 16 * wv + (mm16 ^ ((gq & 1) << 3));

    f32x4 acc[4];
    #pragma unroll
    for (int i = 0; i < 4; ++i) acc[i] = (f32x4){0.f, 0.f, 0.f, 0.f};

    const float* Xnt = X + (size_t)nt * C * HW;

    for (int k0 = 0; k0 < C; k0 += 32) {
        // ---- stage X tile (32k x 64hw) as bf16 hi/lo ----
        {
            const float* src = Xnt + (size_t)(k0 + sk) * HW + hw0 + ss * 8;
            float x[8];
            if (full) {
                float4 a = *(const float4*)src;
                float4 b = *(const float4*)(src + 4);
                x[0] = a.x; x[1] = a.y; x[2] = a.z; x[3] = a.w;
                x[4] = b.x; x[5] = b.y; x[6] = b.z; x[7] = b.w;
            } else {
                #pragma unroll
                for (int i = 0; i < 8; ++i) {
                    int hw = hw0 + ss * 8 + i;
                    x[i] = (hw < HW) ? src[i] : 0.f;
                }
            }
            unsigned int hp[4], lp[4];
            #pragma unroll
            for (int i = 0; i < 4; ++i) {
                unsigned short h0 = f2bf(x[2 * i]), h1 = f2bf(x[2 * i + 1]);
                unsigned short l0 = f2bf(x[2 * i] - bf2f(h0));
                unsigned short l1 = f2bf(x[2 * i + 1] - bf2f(h1));
                hp[i] = (unsigned int)h0 | ((unsigned int)h1 << 16);
                lp[i] = (unsigned int)l0 | ((unsigned int)l1 << 16);
            }
            int xoff = sk * 72 + ((ss * 8) ^ (((sk >> 3) & 1) << 3));
            *(uint4*)&Xh[xoff] = make_uint4(hp[0], hp[1], hp[2], hp[3]);
            *(uint4*)&Xl[xoff] = make_uint4(lp[0], lp[1], lp[2], lp[3]);
        }
        // ---- stage W tile (64r x 32k) pre-packed into fragment order ----
        {
            const float* wsrc = W1 + (size_t)wr * C + k0 + wj * 8;
            float4 a = *(const float4*)wsrc;
            float4 b = *(const float4*)(wsrc + 4);
            float x[8] = {a.x, a.y, a.z, a.w, b.x, b.y, b.z, b.w};
            unsigned int hp[4], lp[4];
            #pragma unroll
            for (int i = 0; i < 4; ++i) {
                unsigned short h0 = f2bf(x[2 * i]), h1 = f2bf(x[2 * i + 1]);
                unsigned short l0 = f2bf(x[2 * i] - bf2f(h0));
                unsigned short l1 = f2bf(x[2 * i + 1] - bf2f(h1));
                hp[i] = (unsigned int)h0 | ((unsigned int)h1 << 16);
                lp[i] = (unsigned int)l0 | ((unsigned int)l1 << 16);
            }
            int woff = ((wr >> 4) * 64 + (wr & 15) + 16 * wj) * 8;
            *(uint4*)&Wh[woff] = make_uint4(hp[0], hp[1], hp[2], hp[3]);
            *(uint4*)&Wl[woff] = make_uint4(lp[0], lp[1], lp[2], lp[3]);
        }
        __syncthreads();

        // ---- gather X fragments (hi, lo) ----
        union { bh8 v; unsigned short u[8]; } fxh, fxl;
        #pragma unroll
        for (int j = 0; j < 8; ++j) {
            fxh.u[j] = Xh[xbase + j * 72];
            fxl.u[j] = Xl[xbase + j * 72];
        }
        // ---- per r-tile: load W fragments, 3 MFMA ----
        #pragma unroll
        for (int rt = 0; rt < 4; ++rt) {
            bh8 wh = *(const bh8*)&Wh[(rt * 64 + l) * 8];
            bh8 wl = *(const bh8*)&Wl[(rt * 64 + l) * 8];
            acc[rt] = __builtin_amdgcn_mfma_f32_16x16x32_bf16(wh, fxh.v, acc[rt], 0, 0, 0);
            acc[rt] = __builtin_amdgcn_mfma_f32_16x16x32_bf16(wh, fxl.v, acc[rt], 0, 0, 0);
            acc[rt] = __builtin_amdgcn_mfma_f32_16x16x32_bf16(wl, fxh.v, acc[rt], 0, 0, 0);
        }
        __syncthreads();
    }

    // ---- epilogue: BN + LReLU, store ----
    const int hw = hw0 + 16 * wv + mm16;
    if (hw < HW) {
        #pragma unroll
        for (int rt = 0; rt < 4; ++rt) {
            #pragma unroll
            for (int reg = 0; reg < 4; ++reg) {
                int r = rt * 16 + 4 * gq + reg;
                float y = (acc[rt][reg] + sCb[r]) * sInv[r] + sAdd[r];
                y = (y >= 0.f) ? y : 0.05f * y;
                s1[((size_t)nt * RR + r) * HW + hw] = y;
            }
        }
    }
}

// ---------------- Kernel B: conv2 (3x1x1 over t, 64->64) + bias ----------------
__global__ __launch_bounds__(256) void convB(const float* __restrict__ s1,
        const float* __restrict__ W2, const float* __restrict__ cb,
        float* __restrict__ s2)
{
    __shared__ float Xs[32][64];
    __shared__ float Ws[32][68];
    const int nt = blockIdx.y;
    const int n = nt >> 3, t = nt & 7;
    const int hw0 = blockIdx.x * 64;
    const int tid = threadIdx.x;
    const int tr = tid & 15, tc = tid >> 4;
    float acc[4][4] = {};

    for (int dt = 0; dt < 3; ++dt) {
        int tp = t + dt - 1;
        if (tp < 0 || tp >= TT) continue;   // uniform per block
        const float* Sp = s1 + (size_t)(n * TT + tp) * RR * HW;
        for (int k0 = 0; k0 < RR; k0 += 32) {
            #pragma unroll
            for (int i = 0; i < 8; ++i) {
                int idx = tid + i * 256;
                int kl = idx >> 6, hwl = idx & 63;
                int hw = hw0 + hwl;
                Xs[kl][hwl] = (hw < HW) ? Sp[(k0 + kl) * HW + hw] : 0.f;
            }
            #pragma unroll
            for (int i = 0; i < 8; ++i) {
                int idx = tid + i * 256;
                int kl = idx & 31, r = idx >> 5;
                Ws[kl][r] = W2[r * 192 + (k0 + kl) * 3 + dt];
            }
            __syncthreads();
            #pragma unroll
            for (int k = 0; k < 32; ++k) {
                float4 xv = *(const float4*)&Xs[k][tr * 4];
                float4 wv = *(const float4*)&Ws[k][tc * 4];
                acc[0][0] += xv.x * wv.x; acc[0][1] += xv.x * wv.y;
                acc[0][2] += xv.x * wv.z; acc[0][3] += xv.x * wv.w;
                acc[1][0] += xv.y * wv.x; acc[1][1] += xv.y * wv.y;
                acc[1][2] += xv.y * wv.z; acc[1][3] += xv.y * wv.w;
                acc[2][0] += xv.z * wv.x; acc[2][1] += xv.z * wv.y;
                acc[2][2] += xv.z * wv.z; acc[2][3] += xv.z * wv.w;
                acc[3][0] += xv.w * wv.x; acc[3][1] += xv.w * wv.y;
                acc[3][2] += xv.w * wv.z; acc[3][3] += xv.w * wv.w;
            }
            __syncthreads();
        }
    }
    #pragma unroll
    for (int j = 0; j < 4; ++j) {
        int r = tc * 4 + j;
        float cbr = cb[r];
        #pragma unroll
        for (int i = 0; i < 4; ++i) {
            int hw = hw0 + tr * 4 + i;
            if (hw < HW)
                s2[((size_t)nt * RR + r) * HW + hw] = acc[i][j] + cbr;
        }
    }
}

// ---------------- Kernel C: conv3 (1x5x5, 64->3, pad 2) + BN + sigmoid ----------------
__global__ __launch_bounds__(256) void convC(const float* __restrict__ s2,
        const float* __restrict__ W3, const float* __restrict__ cb,
        const float* __restrict__ g, const float* __restrict__ bb,
        const float* __restrict__ m, const float* __restrict__ v,
        float* __restrict__ smap)
{
    __shared__ float tile[8][18][36];
    const int nt = blockIdx.y;
    const int half = blockIdx.x;
    const int tid = threadIdx.x;
    const int row0 = half * 14 - 2;
    const int orl = tid / 14;
    const int wsi = tid % 14;
    const int orow = half * 14 + orl;
    const int w0 = wsi * 2;
    float acc[3][2] = {};
    const float* S = s2 + (size_t)nt * RR * HW;

    for (int rc0 = 0; rc0 < RR; rc0 += 8) {
        for (int i = 0; i < 21; ++i) {
            int idx = tid + i * 256;
            if (idx < 5184) {
                int rl = idx / 648;
                int rem = idx - rl * 648;
                int rr = rem / 36;
                int cs = rem - rr * 36;
                int grow = row0 + rr;
                int c = cs - 2;
                float val = 0.f;
                if (grow >= 0 && grow < HH && c >= 0 && c < WW)
                    val = S[(rc0 + rl) * HW + grow * WW + c];
                tile[rl][rr][cs] = val;
            }
        }
        __syncthreads();
        if (tid < 196) {
            #pragma unroll
            for (int rl = 0; rl < 8; ++rl) {
                const float* wr2 = W3 + (rc0 + rl) * 25;
                #pragma unroll
                for (int dh = 0; dh < 5; ++dh) {
                    const float* trow = &tile[rl][orl + dh][w0];
                    float inb[6];
                    #pragma unroll
                    for (int q = 0; q < 6; ++q) inb[q] = trow[q];
                    #pragma unroll
                    for (int dw = 0; dw < 5; ++dw) {
                        float v0 = inb[dw], v1 = inb[dw + 1];
                        #pragma unroll
                        for (int p = 0; p < 3; ++p) {
                            float wv = wr2[p * 1600 + dh * 5 + dw];
                            acc[p][0] += v0 * wv;
                            acc[p][1] += v1 * wv;
                        }
                    }
                }
            }
        }
        __syncthreads();
    }
    if (tid < 196) {
        #pragma unroll
        for (int p = 0; p < 3; ++p) {
            float inv = g[p] / sqrtf(v[p] + EPS);
            float add = bb[p] - m[p] * inv;
            #pragma unroll
            for (int j = 0; j < 2; ++j) {
                float z = (acc[p][j] + cb[p]) * inv + add;
                float sg = 1.f / (1.f + expf(-z));
                smap[((size_t)nt * PP + p) * HW + orow * WW + w0 + j] = sg;
            }
        }
    }
}

// ---------------- Kernel D: weighted node pooling + residual mean ----------------
__global__ __launch_bounds__(256) void poolD(const float* __restrict__ X,
        const float* __restrict__ smap, float* __restrict__ nodes,
        float* __restrict__ out)
{
    const int tid = threadIdx.x;
    const int lane = tid & 63;
    const int gw = blockIdx.x * 4 + (tid >> 6);
    const int c = gw & 511;
    const int nt = gw >> 9;
    const float4* X4 = (const float4*)(X + ((size_t)nt * C + c) * HW);
    const float4* S0 = (const float4*)(smap + (size_t)nt * PP * HW);
    const float4* S1 = S0 + 196;
    const float4* S2 = S1 + 196;
    float sx = 0.f, a0 = 0.f, a1 = 0.f, a2 = 0.f;
    #pragma unroll
    for (int i = 0; i < 4; ++i) {
        int fi = i * 64 + lane;
        if (fi < 196) {
            float4 x = X4[fi];
            float4 p0 = S0[fi], p1 = S1[fi], p2 = S2[fi];
            sx += x.x + x.y + x.z + x.w;
            a0 += x.x * p0.x + x.y * p0.y + x.z * p0.z + x.w * p0.w;
            a1 += x.x * p1.x + x.y * p1.y + x.z * p1.z + x.w * p1.w;
            a2 += x.x * p2.x + x.y * p2.y + x.z * p2.z + x.w * p2.w;
        }
    }
    #pragma unroll
    for (int off = 32; off >= 1; off >>= 1) {
        sx += __shfl_xor(sx, off);
        a0 += __shfl_xor(a0, off);
        a1 += __shfl_xor(a1, off);
        a2 += __shfl_xor(a2, off);
    }
    if (lane == 0) {
        int n = nt >> 3, t = nt & 7;
        const float s = 1.f / 784.f;
        out[((size_t)n * 9 + 1 + t) * C + c] = sx * s;
        float* nd = nodes + ((size_t)n * NN + t * PP) * C + c;
        nd[0]     = a0 * s;
        nd[C]     = a1 * s;
        nd[2 * C] = a2 * s;
    }
}

// ---------------- Kernel E1: A = nodes nodes^T / C, normalized Laplacian L ----------------
__global__ __launch_bounds__(256) void graphL(const float* __restrict__ nodes,
        float* __restrict__ Lg)
{
    __shared__ float4 nds[24][129];
    __shared__ float Amat[24][24];
    __shared__ float dinv[24];
    const int n = blockIdx.x;
    const int tid = threadIdx.x;
    const float4* src = (const float4*)(nodes + (size_t)n * NN * C);
    #pragma unroll
    for (int i = 0; i < 12; ++i) {
        int fi = tid + i * 256;
        int row = fi >> 7, k4 = fi & 127;
        nds[row][k4] = src[row * 128 + k4];
    }
    __syncthreads();
    for (int pair = tid; pair < 576; pair += 256) {
        int i = pair / 24, j = pair - (pair / 24) * 24;
        const float4* ri = &nds[i][0];
        const float4* rj = &nds[j][0];
        float s = 0.f;
        for (int k = 0; k < 128; ++k) {
            float4 a = ri[k], b = rj[k];
            s += a.x * b.x + a.y * b.y + a.z * b.z + a.w * b.w;
        }
        Amat[i][j] = s * (1.f / 512.f);
    }
    __syncthreads();
    if (tid < 24) {
        float d = 0.f;
        for (int j = 0; j < 24; ++j) d += Amat[tid][j];
        d = fmaxf(d, 1e-8f);
        dinv[tid] = 1.f / sqrtf(d);
    }
    __syncthreads();
    for (int pair = tid; pair < 576; pair += 256) {
        int i = pair / 24, j = pair - (pair / 24) * 24;
        Lg[(size_t)n * 576 + pair] = dinv[i] * Amat[i][j] * dinv[j];
    }
}

// ---------------- Kernel G: Y[384,512] = Xin[384,512] @ W^T ----------------
__global__ __launch_bounds__(256) void gemmG(const float* __restrict__ Xin,
        const float* __restrict__ Wm, float* __restrict__ Y)
{
    __shared__ float Xs[32][36];
    __shared__ float Ws[32][66];
    const int o0 = blockIdx.x * 64;
    const int m0 = blockIdx.y * 32;
    const int tid = threadIdx.x;
    const int tr = tid >> 5;
    const int tc = tid & 31;
    float acc[4][2] = {};

    for (int k0 = 0; k0 < 512; k0 += 32) {
        {
            int ml = tid >> 3, k4 = tid & 7;
            float4 xv = *(const float4*)&Xin[(size_t)(m0 + ml) * 512 + k0 + k4 * 4];
            Xs[k4 * 4 + 0][ml] = xv.x; Xs[k4 * 4 + 1][ml] = xv.y;
            Xs[k4 * 4 + 2][ml] = xv.z; Xs[k4 * 4 + 3][ml] = xv.w;
        }
        #pragma unroll
        for (int i = 0; i < 2; ++i) {
            int idx = tid + i * 256;
            int ol = idx >> 3, k4 = idx & 7;
            float4 wv = *(const float4*)&Wm[(size_t)(o0 + ol) * 512 + k0 + k4 * 4];
            Ws[k4 * 4 + 0][ol] = wv.x; Ws[k4 * 4 + 1][ol] = wv.y;
            Ws[k4 * 4 + 2][ol] = wv.z; Ws[k4 * 4 + 3][ol] = wv.w;
        }
        __syncthreads();
        #pragma unroll
        for (int k = 0; k < 32; ++k) {
            float4 xv = *(const float4*)&Xs[k][tr * 4];
            float2 wv = *(const float2*)&Ws[k][tc * 2];
            acc[0][0] += xv.x * wv.x; acc[0][1] += xv.x * wv.y;
            acc[1][0] += xv.y * wv.x; acc[1][1] += xv.y * wv.y;
            acc[2][0] += xv.z * wv.x; acc[2][1] += xv.z * wv.y;
            acc[3][0] += xv.w * wv.x; acc[3][1] += xv.w * wv.y;
        }
        __syncthreads();
    }
    #pragma unroll
    for (int i2 = 0; i2 < 4; ++i2)
        #pragma unroll
        for (int j = 0; j < 2; ++j)
            Y[(size_t)(m0 + tr * 4 + i2) * 512 + o0 + tc * 2 + j] = acc[i2][j];
}

// ---------------- Kernel LX: Xg = lrelu(L @ G) per n ----------------
__global__ __launch_bounds__(256) void applyL(const float* __restrict__ G,
        const float* __restrict__ Lg, float* __restrict__ Xg)
{
    __shared__ float Ls[576];
    const int n = blockIdx.y;
    const int tid = threadIdx.x;
    for (int i = tid; i < 576; i += 256) Ls[i] = Lg[(size_t)n * 576 + i];
    __syncthreads();
    const int o = blockIdx.x * 128 + (tid & 127);
    const int ig = (tid >> 7) * 12;
    float acc[12] = {};
    const float* Gn = G + (size_t)n * NN * 512;
    for (int j = 0; j < 24; ++j) {
        float gv = Gn[j * 512 + o];
        #pragma unroll
        for (int i = 0; i < 12; ++i)
            acc[i] += Ls[(ig + i) * 24 + j] * gv;
    }
    float* Xn = Xg + (size_t)n * NN * 512;
    #pragma unroll
    for (int i = 0; i < 12; ++i) {
        float y = acc[i];
        Xn[(ig + i) * 512 + o] = (y >= 0.f) ? y : 0.05f * y;
    }
}

// ---------------- Kernel E4: attention readout -> out row 0 ----------------
__global__ __launch_bounds__(256) void attE(const float* __restrict__ Xg,
        const float* __restrict__ nodes, const float* __restrict__ Lg,
        const float* __restrict__ aw, const float* __restrict__ ab,
        float* __restrict__ out)
{
    __shared__ float zs[24], ys[24], att[24], Ls[576];
    const int n = blockIdx.x;
    const int tid = threadIdx.x;
    const int lane = tid & 63, wv = tid >> 6;
    for (int i = tid; i < 576; i += 256) Ls[i] = Lg[(size_t)n * 576 + i];
    const float* Xn = Xg + (size_t)n * NN * 512;
    const float* Nn = nodes + (size_t)n * NN * 512;
    for (int i = wv; i < 24; i += 4) {
        float s = 0.f;
        #pragma unroll
        for (int kk = 0; kk < 8; ++kk) {
            int k = kk * 64 + lane;
            s += (Xn[i * 512 + k] + Nn[i * 512 + k]) * aw[k];
        }
        #pragma unroll
        for (int off = 32; off >= 1; off >>= 1) s += __shfl_xor(s, off);
        if (lane == 0) zs[i] = s;
    }
    __syncthreads();
    if (tid < 24) {
        float y = ab[0];
        for (int j = 0; j < 24; ++j) y += Ls[tid * 24 + j] * zs[j];
        ys[tid] = y;
    }
    __syncthreads();
    if (tid < 64) {
        float vv = (tid < 24) ? ys[tid] : -3.4e38f;
        float mx = vv;
        #pragma unroll
        for (int off = 32; off >= 1; off >>= 1) mx = fmaxf(mx, __shfl_xor(mx, off));
        float e = (tid < 24) ? expf(vv - mx) : 0.f;
        float ssum = e;
        #pragma unroll
        for (int off = 32; off >= 1; off >>= 1) ssum += __shfl_xor(ssum, off);
        if (tid < 24) att[tid] = e / ssum;
    }
    __syncthreads();
    for (int c2 = tid; c2 < 512; c2 += 256) {
        float r = 0.f;
        #pragma unroll
        for (int i = 0; i < 24; ++i) r += Xn[i * 512 + c2] * att[i];
        out[(size_t)n * 9 * 512 + c2] = r;
    }
}

extern "C" void kernel_launch(void* const* d_in, const int* in_sizes, int n_in,
                              void* d_out, int out_size, void* d_ws, size_t ws_size,
                              hipStream_t stream)
{
    const float* X   = (const float*)d_in[0];
    const float* w1  = (const float*)d_in[1];
    const float* b1c = (const float*)d_in[2];
    const float* g1  = (const float*)d_in[3];
    const float* b1  = (const float*)d_in[4];
    const float* m1  = (const float*)d_in[5];
    const float* v1  = (const float*)d_in[6];
    const float* w2  = (const float*)d_in[7];
    const float* b2c = (const float*)d_in[8];
    const float* w3  = (const float*)d_in[9];
    const float* b3c = (const float*)d_in[10];
    const float* g2  = (const float*)d_in[11];
    const float* b2  = (const float*)d_in[12];
    const float* m2  = (const float*)d_in[13];
    const float* v2  = (const float*)d_in[14];
    const float* gw0 = (const float*)d_in[15];
    const float* gw1 = (const float*)d_in[16];
    const float* aw  = (const float*)d_in[17];
    const float* ab  = (const float*)d_in[18];
    float* out = (float*)d_out;

    float* ws    = (float*)d_ws;
    float* s1    = ws;
    float* s2    = s1 + (size_t)NT * RR * HW;
    float* smap  = s2 + (size_t)NT * RR * HW;
    float* nodes = smap + (size_t)NT * PP * HW;
    float* Lg    = nodes + (size_t)NB * NN * C;
    float* gt    = Lg + (size_t)NB * NN * NN;
    float* xa    = gt + (size_t)NB * NN * C;
    float* xb    = xa + (size_t)NB * NN * C;

    convA_mfma<<<dim3(13, NT), 256, 0, stream>>>(X, w1, b1c, g1, b1, m1, v1, s1);
    convB<<<dim3(13, NT), 256, 0, stream>>>(s1, w2, b2c, s2);
    convC<<<dim3(2, NT), 256, 0, stream>>>(s2, w3, b3c, g2, b2, m2, v2, smap);
    poolD<<<dim3(16384), 256, 0, stream>>>(X, smap, nodes, out);
    graphL<<<dim3(NB), 256, 0, stream>>>(nodes, Lg);
    gemmG<<<dim3(8, 12), 256, 0, stream>>>(nodes, gw0, gt);
    applyL<<<dim3(4, NB), 256, 0, stream>>>(gt, Lg, xa);
    gemmG<<<dim3(8, 12), 256, 0, stream>>>(xa, gw1, gt);
    applyL<<<dim3(4, NB), 256, 0, stream>>>(gt, Lg, xb);
    attE<<<dim3(NB), 256, 0, stream>>>(xb, nodes, Lg, aw, ab, out);
}

// Round 4
// 498.312 us; speedup vs baseline: 1.3503x; 1.2028x over previous
//
#include <hip/hip_runtime.h>
#include <hip/hip_bf16.h>
#include <math.h>

#define NT 128
#define NB 16
#define TT 8
#define C 512
#define RR 64
#define HW 784
#define HH 28
#define WW 28
#define PP 3
#define NN 24
#define EPS 1e-5f

typedef __attribute__((ext_vector_type(8))) short bh8;
typedef __attribute__((ext_vector_type(4))) float f32x4;
typedef unsigned short u16;

static __device__ inline u16 f2bf(float f) {
    __hip_bfloat16 h = __float2bfloat16(f);
    return *(u16*)&h;
}
static __device__ inline float bf2f(u16 u) {
    __hip_bfloat16 h;
    *(u16*)&h = u;
    return __bfloat162float(h);
}

// ---------------- Kernel A (MFMA): conv1 (1x1x1, C->64) + BN + LReLU ----------------
// Writes s1 as bf16 hi/lo pair so convB can MFMA directly without re-splitting.
__global__ __launch_bounds__(256) void convA_mfma(const float* __restrict__ X,
        const float* __restrict__ W1, const float* __restrict__ cb,
        const float* __restrict__ g, const float* __restrict__ bb,
        const float* __restrict__ m, const float* __restrict__ v,
        u16* __restrict__ s1h, u16* __restrict__ s1l)
{
    __shared__ u16 Xh[32 * 72];
    __shared__ u16 Xl[32 * 72];
    __shared__ u16 Wh[4 * 64 * 8];
    __shared__ u16 Wl[4 * 64 * 8];
    __shared__ float sInv[64], sAdd[64], sCb[64];

    const int nt  = blockIdx.y;
    const int hw0 = blockIdx.x * 64;
    const int tid = threadIdx.x;

    if (tid < 64) {
        float inv = g[tid] * rsqrtf(v[tid] + EPS);
        sInv[tid] = inv;
        sAdd[tid] = bb[tid] - m[tid] * inv;
        sCb[tid]  = cb[tid];
    }

    const int sk = tid >> 3;
    const int ss = tid & 7;
    const int wr = tid >> 2;
    const int wj = tid & 3;
    const bool full = (hw0 + 64 <= HW);

    const int wv = tid >> 6;
    const int l  = tid & 63;
    const int gq = l >> 4;
    const int mm16 = l & 15;
    const int xbase = (gq * 8) * 72 + 16 * wv + (mm16 ^ ((gq & 1) << 3));

    f32x4 acc[4];
    #pragma unroll
    for (int i = 0; i < 4; ++i) acc[i] = (f32x4){0.f, 0.f, 0.f, 0.f};

    const float* Xnt = X + (size_t)nt * C * HW;

    for (int k0 = 0; k0 < C; k0 += 32) {
        {
            const float* src = Xnt + (size_t)(k0 + sk) * HW + hw0 + ss * 8;
            float x[8];
            if (full) {
                float4 a = *(const float4*)src;
                float4 b = *(const float4*)(src + 4);
                x[0] = a.x; x[1] = a.y; x[2] = a.z; x[3] = a.w;
                x[4] = b.x; x[5] = b.y; x[6] = b.z; x[7] = b.w;
            } else {
                #pragma unroll
                for (int i = 0; i < 8; ++i) {
                    int hw = hw0 + ss * 8 + i;
                    x[i] = (hw < HW) ? src[i] : 0.f;
                }
            }
            unsigned int hp[4], lp[4];
            #pragma unroll
            for (int i = 0; i < 4; ++i) {
                u16 h0 = f2bf(x[2 * i]), h1 = f2bf(x[2 * i + 1]);
                u16 l0 = f2bf(x[2 * i] - bf2f(h0));
                u16 l1 = f2bf(x[2 * i + 1] - bf2f(h1));
                hp[i] = (unsigned int)h0 | ((unsigned int)h1 << 16);
                lp[i] = (unsigned int)l0 | ((unsigned int)l1 << 16);
            }
            int xoff = sk * 72 + ((ss * 8) ^ (((sk >> 3) & 1) << 3));
            *(uint4*)&Xh[xoff] = make_uint4(hp[0], hp[1], hp[2], hp[3]);
            *(uint4*)&Xl[xoff] = make_uint4(lp[0], lp[1], lp[2], lp[3]);
        }
        {
            const float* wsrc = W1 + (size_t)wr * C + k0 + wj * 8;
            float4 a = *(const float4*)wsrc;
            float4 b = *(const float4*)(wsrc + 4);
            float x[8] = {a.x, a.y, a.z, a.w, b.x, b.y, b.z, b.w};
            unsigned int hp[4], lp[4];
            #pragma unroll
            for (int i = 0; i < 4; ++i) {
                u16 h0 = f2bf(x[2 * i]), h1 = f2bf(x[2 * i + 1]);
                u16 l0 = f2bf(x[2 * i] - bf2f(h0));
                u16 l1 = f2bf(x[2 * i + 1] - bf2f(h1));
                hp[i] = (unsigned int)h0 | ((unsigned int)h1 << 16);
                lp[i] = (unsigned int)l0 | ((unsigned int)l1 << 16);
            }
            int woff = ((wr >> 4) * 64 + (wr & 15) + 16 * wj) * 8;
            *(uint4*)&Wh[woff] = make_uint4(hp[0], hp[1], hp[2], hp[3]);
            *(uint4*)&Wl[woff] = make_uint4(lp[0], lp[1], lp[2], lp[3]);
        }
        __syncthreads();

        union { bh8 v; u16 u[8]; } fxh, fxl;
        #pragma unroll
        for (int j = 0; j < 8; ++j) {
            fxh.u[j] = Xh[xbase + j * 72];
            fxl.u[j] = Xl[xbase + j * 72];
        }
        #pragma unroll
        for (int rt = 0; rt < 4; ++rt) {
            bh8 wh = *(const bh8*)&Wh[(rt * 64 + l) * 8];
            bh8 wl = *(const bh8*)&Wl[(rt * 64 + l) * 8];
            acc[rt] = __builtin_amdgcn_mfma_f32_16x16x32_bf16(wh, fxh.v, acc[rt], 0, 0, 0);
            acc[rt] = __builtin_amdgcn_mfma_f32_16x16x32_bf16(wh, fxl.v, acc[rt], 0, 0, 0);
            acc[rt] = __builtin_amdgcn_mfma_f32_16x16x32_bf16(wl, fxh.v, acc[rt], 0, 0, 0);
        }
        __syncthreads();
    }

    const int hw = hw0 + 16 * wv + mm16;
    if (hw < HW) {
        #pragma unroll
        for (int rt = 0; rt < 4; ++rt) {
            #pragma unroll
            for (int reg = 0; reg < 4; ++reg) {
                int r = rt * 16 + 4 * gq + reg;
                float y = (acc[rt][reg] + sCb[r]) * sInv[r] + sAdd[r];
                y = (y >= 0.f) ? y : 0.05f * y;
                size_t idx = ((size_t)nt * RR + r) * HW + hw;
                u16 h = f2bf(y);
                s1h[idx] = h;
                s1l[idx] = f2bf(y - bf2f(h));
            }
        }
    }
}

// ---------------- Kernel B (MFMA): conv2 (3x1x1 over t, 64->64) + bias ----------------
__global__ __launch_bounds__(256) void convB_mfma(const u16* __restrict__ s1h,
        const u16* __restrict__ s1l, const float* __restrict__ W2,
        const float* __restrict__ cb, float* __restrict__ s2)
{
    __shared__ u16 Xh[32 * 72];
    __shared__ u16 Xl[32 * 72];
    __shared__ u16 Wh[6 * 4 * 64 * 8];   // [dt*2+kc][rt][lane][8]
    __shared__ u16 Wl[6 * 4 * 64 * 8];

    const int nt  = blockIdx.y;
    const int n = nt >> 3, t = nt & 7;
    const int hw0 = blockIdx.x * 64;
    const int tid = threadIdx.x;
    const bool full = (hw0 + 64 <= HW);

    // ---- stage ALL weights, pre-packed fragments ----
    const int wr = tid >> 2, wj = tid & 3;
    #pragma unroll
    for (int dk = 0; dk < 6; ++dk) {
        int dt = dk >> 1, kc = dk & 1;
        const float* wsrc = W2 + (size_t)wr * 192 + (kc * 32 + wj * 8) * 3 + dt;
        float x[8];
        #pragma unroll
        for (int i = 0; i < 8; ++i) x[i] = wsrc[i * 3];
        unsigned int hp[4], lp[4];
        #pragma unroll
        for (int i = 0; i < 4; ++i) {
            u16 h0 = f2bf(x[2 * i]), h1 = f2bf(x[2 * i + 1]);
            u16 l0 = f2bf(x[2 * i] - bf2f(h0));
            u16 l1 = f2bf(x[2 * i + 1] - bf2f(h1));
            hp[i] = (unsigned int)h0 | ((unsigned int)h1 << 16);
            lp[i] = (unsigned int)l0 | ((unsigned int)l1 << 16);
        }
        int woff = dk * 2048 + ((wr >> 4) * 64 + (wr & 15) + 16 * wj) * 8;
        *(uint4*)&Wh[woff] = make_uint4(hp[0], hp[1], hp[2], hp[3]);
        *(uint4*)&Wl[woff] = make_uint4(lp[0], lp[1], lp[2], lp[3]);
    }
    __syncthreads();

    const int sk = tid >> 3, ss = tid & 7;
    const int wv = tid >> 6, l = tid & 63;
    const int gq = l >> 4, mm16 = l & 15;
    const int xbase = (gq * 8) * 72 + 16 * wv + (mm16 ^ ((gq & 1) << 3));
    const int xoff = sk * 72 + ((ss * 8) ^ (((sk >> 3) & 1) << 3));

    f32x4 acc[4];
    #pragma unroll
    for (int i = 0; i < 4; ++i) acc[i] = (f32x4){0.f, 0.f, 0.f, 0.f};

    for (int dt = 0; dt < 3; ++dt) {
        int tp = t + dt - 1;
        if (tp < 0 || tp >= TT) continue;   // block-uniform
        const size_t pbase = (size_t)(n * TT + tp) * RR * HW;
        #pragma unroll
        for (int kc = 0; kc < 2; ++kc) {
            const size_t roff = pbase + (size_t)(kc * 32 + sk) * HW + hw0 + ss * 8;
            uint4 hv, lv;
            if (full) {
                hv = *(const uint4*)(s1h + roff);
                lv = *(const uint4*)(s1l + roff);
            } else {
                u16 ha[8], la[8];
                #pragma unroll
                for (int i = 0; i < 8; ++i) {
                    int hw = hw0 + ss * 8 + i;
                    ha[i] = (hw < HW) ? s1h[roff + i] : (u16)0;
                    la[i] = (hw < HW) ? s1l[roff + i] : (u16)0;
                }
                hv = *(uint4*)ha; lv = *(uint4*)la;
            }
            __syncthreads();   // protect previous compute before overwrite
            *(uint4*)&Xh[xoff] = hv;
            *(uint4*)&Xl[xoff] = lv;
            __syncthreads();

            union { bh8 v; u16 u[8]; } fxh, fxl;
            #pragma unroll
            for (int j = 0; j < 8; ++j) {
                fxh.u[j] = Xh[xbase + j * 72];
                fxl.u[j] = Xl[xbase + j * 72];
            }
            const int dk = dt * 2 + kc;
            #pragma unroll
            for (int rt = 0; rt < 4; ++rt) {
                bh8 wh = *(const bh8*)&Wh[dk * 2048 + (rt * 64 + l) * 8];
                bh8 wl = *(const bh8*)&Wl[dk * 2048 + (rt * 64 + l) * 8];
                acc[rt] = __builtin_amdgcn_mfma_f32_16x16x32_bf16(wh, fxh.v, acc[rt], 0, 0, 0);
                acc[rt] = __builtin_amdgcn_mfma_f32_16x16x32_bf16(wh, fxl.v, acc[rt], 0, 0, 0);
                acc[rt] = __builtin_amdgcn_mfma_f32_16x16x32_bf16(wl, fxh.v, acc[rt], 0, 0, 0);
            }
        }
    }

    const int hw = hw0 + 16 * wv + mm16;
    if (hw < HW) {
        #pragma unroll
        for (int rt = 0; rt < 4; ++rt) {
            #pragma unroll
            for (int reg = 0; reg < 4; ++reg) {
                int r = rt * 16 + 4 * gq + reg;
                s2[((size_t)nt * RR + r) * HW + hw] = acc[rt][reg] + cb[r];
            }
        }
    }
}

// ---------------- Kernel C (rewrite): conv3 (1x5x5, 64->3, pad 2) ----------------
// No LDS. Sliding 5x5 register window; weights in SGPRs (uniform loads).
// Work item = (chgroup of 8, nt, 7-row band); 2 items per wave (half-wave = 28 cols).
// Writes per-chgroup partials; convC_fin reduces + BN + sigmoid.
__global__ __launch_bounds__(256) void convC_sw(const float* __restrict__ s2,
        const float* __restrict__ W3, float* __restrict__ partial)
{
    const int tid  = threadIdx.x;
    const int wave = tid >> 6;
    const int lane = tid & 63;
    const int half = lane >> 5;
    const int col  = lane & 31;            // 0..27 valid
    const int item = blockIdx.x * 8 + wave * 2 + half;   // 0..4095
    const int band = item & 3;
    const int nt   = (item >> 2) & 127;
    int cg = item >> 9;                    // wave-uniform by construction
    cg = __builtin_amdgcn_readfirstlane(cg);

    const int row0 = band * 7;             // output rows row0..row0+6
    const bool cok = (col < 28);

    float acc[3][7];
    #pragma unroll
    for (int p = 0; p < 3; ++p)
        #pragma unroll
        for (int r = 0; r < 7; ++r) acc[p][r] = 0.f;

    for (int chi = 0; chi < 8; ++chi) {
        // uniform weight loads -> SGPRs
        float wgt[75];
        #pragma unroll
        for (int p = 0; p < 3; ++p)
            #pragma unroll
            for (int q = 0; q < 25; ++q)
                wgt[p * 25 + q] = W3[(size_t)(p * 64 + cg * 8 + chi) * 25 + q];

        const float* src = s2 + ((size_t)nt * RR + cg * 8 + chi) * HW;
        float w[5][5];

        // prologue: input rows row0-2 .. row0+1 into slots 0..3
        #pragma unroll
        for (int rr = 0; rr < 4; ++rr) {
            int R = row0 - 2 + rr;
            bool rok = (R >= 0) & (R < HH);
            #pragma unroll
            for (int j = 0; j < 5; ++j) {
                int cc = col - 2 + j;
                bool ok = rok & cok & (cc >= 0) & (cc < WW);
                w[rr][j] = ok ? src[R * WW + cc] : 0.f;
            }
        }
        // 7 output rows
        #pragma unroll
        for (int r = 0; r < 7; ++r) {
            {   // load input row row0+2+r into slot (r+4)%5
                int R = row0 + 2 + r;
                bool rok = (R < HH);       // R >= 2 always
                int slot = (r + 4) % 5;
                #pragma unroll
                for (int j = 0; j < 5; ++j) {
                    int cc = col - 2 + j;
                    bool ok = rok & cok & (cc >= 0) & (cc < WW);
                    w[slot][j] = ok ? src[R * WW + cc] : 0.f;
                }
            }
            #pragma unroll
            for (int p = 0; p < 3; ++p)
                #pragma unroll
                for (int dh = 0; dh < 5; ++dh)
                    #pragma unroll
                    for (int dw = 0; dw < 5; ++dw)
                        acc[p][r] += w[(r + dh) % 5][dw] * wgt[p * 25 + dh * 5 + dw];
        }
    }

    if (cok) {
        #pragma unroll
        for (int p = 0; p < 3; ++p)
            #pragma unroll
            for (int r = 0; r < 7; ++r)
                partial[(((size_t)cg * 128 + nt) * 3 + p) * HW + (row0 + r) * WW + col]
                    = acc[p][r];
    }
}

// ---------------- Kernel C2: reduce partials + bias + BN + sigmoid ----------------
__global__ __launch_bounds__(256) void convC_fin(const float* __restrict__ partial,
        const float* __restrict__ cb, const float* __restrict__ g,
        const float* __restrict__ bb, const float* __restrict__ m,
        const float* __restrict__ v, float* __restrict__ smap)
{
    const int idx = blockIdx.x * 256 + threadIdx.x;
    const int total = 128 * 3 * HW;
    if (idx >= total) return;
    const int p = (idx / HW) % 3;
    float a = cb[p];
    #pragma unroll
    for (int gg = 0; gg < 8; ++gg) a += partial[(size_t)gg * total + idx];
    float inv = g[p] * rsqrtf(v[p] + EPS);
    float z = a * inv + (bb[p] - m[p] * inv);
    smap[idx] = 1.f / (1.f + expf(-z));
}

// ---------------- Kernel D: weighted node pooling + residual mean ----------------
__global__ __launch_bounds__(256) void poolD(const float* __restrict__ X,
        const float* __restrict__ smap, float* __restrict__ nodes,
        float* __restrict__ out)
{
    const int tid = threadIdx.x;
    const int lane = tid & 63;
    const int gw = blockIdx.x * 4 + (tid >> 6);
    const int c = gw & 511;
    const int nt = gw >> 9;
    const float4* X4 = (const float4*)(X + ((size_t)nt * C + c) * HW);
    const float4* S0 = (const float4*)(smap + (size_t)nt * PP * HW);
    const float4* S1 = S0 + 196;
    const float4* S2 = S1 + 196;
    float sx = 0.f, a0 = 0.f, a1 = 0.f, a2 = 0.f;
    #pragma unroll
    for (int i = 0; i < 4; ++i) {
        int fi = i * 64 + lane;
        if (fi < 196) {
            float4 x = X4[fi];
            float4 p0 = S0[fi], p1 = S1[fi], p2 = S2[fi];
            sx += x.x + x.y + x.z + x.w;
            a0 += x.x * p0.x + x.y * p0.y + x.z * p0.z + x.w * p0.w;
            a1 += x.x * p1.x + x.y * p1.y + x.z * p1.z + x.w * p1.w;
            a2 += x.x * p2.x + x.y * p2.y + x.z * p2.z + x.w * p2.w;
        }
    }
    #pragma unroll
    for (int off = 32; off >= 1; off >>= 1) {
        sx += __shfl_xor(sx, off);
        a0 += __shfl_xor(a0, off);
        a1 += __shfl_xor(a1, off);
        a2 += __shfl_xor(a2, off);
    }
    if (lane == 0) {
        int n = nt >> 3, t = nt & 7;
        const float s = 1.f / 784.f;
        out[((size_t)n * 9 + 1 + t) * C + c] = sx * s;
        float* nd = nodes + ((size_t)n * NN + t * PP) * C + c;
        nd[0]     = a0 * s;
        nd[C]     = a1 * s;
        nd[2 * C] = a2 * s;
    }
}

// ---------------- Kernel E1: normalized Laplacian ----------------
__global__ __launch_bounds__(256) void graphL(const float* __restrict__ nodes,
        float* __restrict__ Lg)
{
    __shared__ float4 nds[24][129];
    __shared__ float Amat[24][24];
    __shared__ float dinv[24];
    const int n = blockIdx.x;
    const int tid = threadIdx.x;
    const float4* src = (const float4*)(nodes + (size_t)n * NN * C);
    #pragma unroll
    for (int i = 0; i < 12; ++i) {
        int fi = tid + i * 256;
        int row = fi >> 7, k4 = fi & 127;
        nds[row][k4] = src[row * 128 + k4];
    }
    __syncthreads();
    for (int pair = tid; pair < 576; pair += 256) {
        int i = pair / 24, j = pair - (pair / 24) * 24;
        const float4* ri = &nds[i][0];
        const float4* rj = &nds[j][0];
        float s = 0.f;
        for (int k = 0; k < 128; ++k) {
            float4 a = ri[k], b = rj[k];
            s += a.x * b.x + a.y * b.y + a.z * b.z + a.w * b.w;
        }
        Amat[i][j] = s * (1.f / 512.f);
    }
    __syncthreads();
    if (tid < 24) {
        float d = 0.f;
        for (int j = 0; j < 24; ++j) d += Amat[tid][j];
        d = fmaxf(d, 1e-8f);
        dinv[tid] = 1.f / sqrtf(d);
    }
    __syncthreads();
    for (int pair = tid; pair < 576; pair += 256) {
        int i = pair / 24, j = pair - (pair / 24) * 24;
        Lg[(size_t)n * 576 + pair] = dinv[i] * Amat[i][j] * dinv[j];
    }
}

// ---------------- Kernel G: Y[384,512] = Xin[384,512] @ W^T ----------------
__global__ __launch_bounds__(256) void gemmG(const float* __restrict__ Xin,
        const float* __restrict__ Wm, float* __restrict__ Y)
{
    __shared__ float Xs[32][36];
    __shared__ float Ws[32][66];
    const int o0 = blockIdx.x * 64;
    const int m0 = blockIdx.y * 32;
    const int tid = threadIdx.x;
    const int tr = tid >> 5;
    const int tc = tid & 31;
    float acc[4][2] = {};

    for (int k0 = 0; k0 < 512; k0 += 32) {
        {
            int ml = tid >> 3, k4 = tid & 7;
            float4 xv = *(const float4*)&Xin[(size_t)(m0 + ml) * 512 + k0 + k4 * 4];
            Xs[k4 * 4 + 0][ml] = xv.x; Xs[k4 * 4 + 1][ml] = xv.y;
            Xs[k4 * 4 + 2][ml] = xv.z; Xs[k4 * 4 + 3][ml] = xv.w;
        }
        #pragma unroll
        for (int i = 0; i < 2; ++i) {
            int idx = tid + i * 256;
            int ol = idx >> 3, k4 = idx & 7;
            float4 wv = *(const float4*)&Wm[(size_t)(o0 + ol) * 512 + k0 + k4 * 4];
            Ws[k4 * 4 + 0][ol] = wv.x; Ws[k4 * 4 + 1][ol] = wv.y;
            Ws[k4 * 4 + 2][ol] = wv.z; Ws[k4 * 4 + 3][ol] = wv.w;
        }
        __syncthreads();
        #pragma unroll
        for (int k = 0; k < 32; ++k) {
            float4 xv = *(const float4*)&Xs[k][tr * 4];
            float2 wv = *(const float2*)&Ws[k][tc * 2];
            acc[0][0] += xv.x * wv.x; acc[0][1] += xv.x * wv.y;
            acc[1][0] += xv.y * wv.x; acc[1][1] += xv.y * wv.y;
            acc[2][0] += xv.z * wv.x; acc[2][1] += xv.z * wv.y;
            acc[3][0] += xv.w * wv.x; acc[3][1] += xv.w * wv.y;
        }
        __syncthreads();
    }
    #pragma unroll
    for (int i2 = 0; i2 < 4; ++i2)
        #pragma unroll
        for (int j = 0; j < 2; ++j)
            Y[(size_t)(m0 + tr * 4 + i2) * 512 + o0 + tc * 2 + j] = acc[i2][j];
}

// ---------------- Kernel LX: Xg = lrelu(L @ G) per n ----------------
__global__ __launch_bounds__(256) void applyL(const float* __restrict__ G,
        const float* __restrict__ Lg, float* __restrict__ Xg)
{
    __shared__ float Ls[576];
    const int n = blockIdx.y;
    const int tid = threadIdx.x;
    for (int i = tid; i < 576; i += 256) Ls[i] = Lg[(size_t)n * 576 + i];
    __syncthreads();
    const int o = blockIdx.x * 128 + (tid & 127);
    const int ig = (tid >> 7) * 12;
    float acc[12] = {};
    const float* Gn = G + (size_t)n * NN * 512;
    for (int j = 0; j < 24; ++j) {
        float gv = Gn[j * 512 + o];
        #pragma unroll
        for (int i = 0; i < 12; ++i)
            acc[i] += Ls[(ig + i) * 24 + j] * gv;
    }
    float* Xn = Xg + (size_t)n * NN * 512;
    #pragma unroll
    for (int i = 0; i < 12; ++i) {
        float y = acc[i];
        Xn[(ig + i) * 512 + o] = (y >= 0.f) ? y : 0.05f * y;
    }
}

// ---------------- Kernel E4: attention readout -> out row 0 ----------------
__global__ __launch_bounds__(256) void attE(const float* __restrict__ Xg,
        const float* __restrict__ nodes, const float* __restrict__ Lg,
        const float* __restrict__ aw, const float* __restrict__ ab,
        float* __restrict__ out)
{
    __shared__ float zs[24], ys[24], att[24], Ls[576];
    const int n = blockIdx.x;
    const int tid = threadIdx.x;
    const int lane = tid & 63, wv = tid >> 6;
    for (int i = tid; i < 576; i += 256) Ls[i] = Lg[(size_t)n * 576 + i];
    const float* Xn = Xg + (size_t)n * NN * 512;
    const float* Nn = nodes + (size_t)n * NN * 512;
    for (int i = wv; i < 24; i += 4) {
        float s = 0.f;
        #pragma unroll
        for (int kk = 0; kk < 8; ++kk) {
            int k = kk * 64 + lane;
            s += (Xn[i * 512 + k] + Nn[i * 512 + k]) * aw[k];
        }
        #pragma unroll
        for (int off = 32; off >= 1; off >>= 1) s += __shfl_xor(s, off);
        if (lane == 0) zs[i] = s;
    }
    __syncthreads();
    if (tid < 24) {
        float y = ab[0];
        for (int j = 0; j < 24; ++j) y += Ls[tid * 24 + j] * zs[j];
        ys[tid] = y;
    }
    __syncthreads();
    if (tid < 64) {
        float vv = (tid < 24) ? ys[tid] : -3.4e38f;
        float mx = vv;
        #pragma unroll
        for (int off = 32; off >= 1; off >>= 1) mx = fmaxf(mx, __shfl_xor(mx, off));
        float e = (tid < 24) ? expf(vv - mx) : 0.f;
        float ssum = e;
        #pragma unroll
        for (int off = 32; off >= 1; off >>= 1) ssum += __shfl_xor(ssum, off);
        if (tid < 24) att[tid] = e / ssum;
    }
    __syncthreads();
    for (int c2 = tid; c2 < 512; c2 += 256) {
        float r = 0.f;
        #pragma unroll
        for (int i = 0; i < 24; ++i) r += Xn[i * 512 + c2] * att[i];
        out[(size_t)n * 9 * 512 + c2] = r;
    }
}

extern "C" void kernel_launch(void* const* d_in, const int* in_sizes, int n_in,
                              void* d_out, int out_size, void* d_ws, size_t ws_size,
                              hipStream_t stream)
{
    const float* X   = (const float*)d_in[0];
    const float* w1  = (const float*)d_in[1];
    const float* b1c = (const float*)d_in[2];
    const float* g1  = (const float*)d_in[3];
    const float* b1  = (const float*)d_in[4];
    const float* m1  = (const float*)d_in[5];
    const float* v1  = (const float*)d_in[6];
    const float* w2  = (const float*)d_in[7];
    const float* b2c = (const float*)d_in[8];
    const float* w3  = (const float*)d_in[9];
    const float* b3c = (const float*)d_in[10];
    const float* g2  = (const float*)d_in[11];
    const float* b2  = (const float*)d_in[12];
    const float* m2  = (const float*)d_in[13];
    const float* v2  = (const float*)d_in[14];
    const float* gw0 = (const float*)d_in[15];
    const float* gw1 = (const float*)d_in[16];
    const float* aw  = (const float*)d_in[17];
    const float* ab  = (const float*)d_in[18];
    float* out = (float*)d_out;

    const size_t S1N = (size_t)NT * RR * HW;   // 6422528
    u16*   s1h   = (u16*)d_ws;
    u16*   s1l   = s1h + S1N;
    float* part  = (float*)d_ws;               // overlays s1h/s1l (dead after convB)
    float* s2    = (float*)(s1l + S1N);
    float* smap  = s2 + S1N;
    float* nodes = smap + (size_t)NT * PP * HW;
    float* Lg    = nodes + (size_t)NB * NN * C;
    float* gt    = Lg + (size_t)NB * NN * NN;
    float* xa    = gt + (size_t)NB * NN * C;
    float* xb    = xa + (size_t)NB * NN * C;

    convA_mfma<<<dim3(13, NT), 256, 0, stream>>>(X, w1, b1c, g1, b1, m1, v1, s1h, s1l);
    convB_mfma<<<dim3(13, NT), 256, 0, stream>>>(s1h, s1l, w2, b2c, s2);
    convC_sw<<<dim3(512), 256, 0, stream>>>(s2, w3, part);
    convC_fin<<<dim3(1176), 256, 0, stream>>>(part, b3c, g2, b2, m2, v2, smap);
    poolD<<<dim3(16384), 256, 0, stream>>>(X, smap, nodes, out);
    graphL<<<dim3(NB), 256, 0, stream>>>(nodes, Lg);
    gemmG<<<dim3(8, 12), 256, 0, stream>>>(nodes, gw0, gt);
    applyL<<<dim3(4, NB), 256, 0, stream>>>(gt, Lg, xa);
    gemmG<<<dim3(8, 12), 256, 0, stream>>>(xa, gw1, gt);
    applyL<<<dim3(4, NB), 256, 0, stream>>>(gt, Lg, xb);
    attE<<<dim3(NB), 256, 0, stream>>>(xb, nodes, Lg, aw, ab, out);
}